// Round 10
// baseline (151.359 us; speedup 1.0000x reference)
//
#include <hip/hip_runtime.h>

// Problem constants
#define NB     64      // batch
#define TT     2048    // time
#define INQ    8       // input size
#define CC     2       // channels
#define MM     10      // hidden m
#define ROWP   12      // padded row floats (48 B)
#define MATS   124     // matrix stride in LDS tree (124%32=28 -> lvl1 8-way max)
#define SKSTR  12      // sktri row stride floats (quad lanes 2-way banks = free)
#define SLEN   6       // sequential steps per quad segment
#define SEGS   64      // segments per block (256 thr / 4 lanes)
#define NCHUNK 6       // chunks per chain -> grid 768 = exactly 3 blocks/CU
#define NCHAIN (NB*CC)
#define NBLK   (NCHAIN*NCHUNK)      // 768
#define WSMAT  120                  // padded floats per ws matrix
#define CTRO   (NCHAIN*NCHUNK*WSMAT) // counter float offset in ws (92160)

// Upper-triangle index for (k,j), k<j, into 45-element array
__device__ __forceinline__ constexpr int triIdx(int k, int j) {
    return k * 10 + j - ((k + 1) * (k + 2)) / 2;
}

// Broadcast lane (quad base + SRC)'s value to all 4 lanes of the quad.
template <int SRC>
__device__ __forceinline__ float dpp_qbcast(float v) {
    const int i = __float_as_int(v);
    const int r = __builtin_amdgcn_update_dpp(i, i, SRC * 0x55, 0xF, 0xF, true);
    return __int_as_float(r);
}

// One block per (chain, chunk). Quad owns a segment of SLEN=6 steps; rows
// split 3/3/2/2 (136-160 VGPR no-spill point; plain launch_bounds(256) is
// the only allocator-safe config — (256,2)/(256,4) both spilled, r4/r8).
// Grid 768 = 3 blocks/CU = 3 waves/SIMD (r9 ran 2/SIMD, VALUBusy 58%).
// After the in-block 6-level tree, the chunk product goes to ws; the LAST
// block (device atomic counter) combines all 128 chains' 6 chunk products
// and writes out — single kernel, no second launch (r6-r9 showed a ~45 µs
// total-minus-serial gap consistent with per-launch overhead).
__global__ __launch_bounds__(256)
void dev_serial(const float* __restrict__ x,
                const float* __restrict__ A,
                float* __restrict__ ws,
                float* __restrict__ out)
{
    __shared__ __align__(16) float sk_s[48 * SKSTR];    // 2304 B (rows >=45 zero)
    __shared__ __align__(16) float buf_s[SEGS * MATS];  // 31744 B tree buffer
    __shared__ int last_s;

    const int tid   = threadIdx.x;
    const int chain = blockIdx.x / NCHUNK;
    const int qt    = blockIdx.x - chain * NCHUNK;
    const int n     = chain >> 1;        // / CC
    const int c     = chain & 1;

    // Precompute sktri[t][ip] = A[c][ip][k][j] - A[c][ip][j][k], t <-> (k<j)
    for (int e = tid; e < 48 * INQ; e += 256) {
        const int t  = e >> 3;
        const int ip = e & 7;
        float v = 0.0f;
        if (t < 45) {
            int k = 0, rem = t;
            while (rem >= 9 - k) { rem -= (9 - k); ++k; }
            const int j = k + 1 + rem;
            const float* Ab = A + (size_t)(c * INQ + ip) * (MM * MM);
            v = Ab[k * MM + j] - Ab[j * MM + k];
        }
        sk_s[t * SKSTR + ip] = v;
    }
    for (int t = tid; t < 48; t += 256) {
        sk_s[t * SKSTR + 8]  = 0.0f; sk_s[t * SKSTR + 9]  = 0.0f;
        sk_s[t * SKSTR + 10] = 0.0f; sk_s[t * SKSTR + 11] = 0.0f;
    }
    __syncthreads();

    const int seg = tid >> 2;
    const int q   = tid & 3;                       // lane within quad
    const int r0  = (q < 2) ? 3 * q : (q == 2 ? 6 : 8);
    const int rc  = (q < 2) ? 3 : 2;               // real rows owned

    // Running product rows (identity; dummy 3rd row on q>=2 lanes never stored)
    float R[3][MM];
    #pragma unroll
    for (int r = 0; r < 3; ++r) {
        const int gi = (r0 + r > 9) ? 9 : (r0 + r);
        #pragma unroll
        for (int j = 0; j < MM; ++j)
            R[r][j] = (j == gi) ? 1.0f : 0.0f;
    }

    const float* xb = x + (size_t)n * TT * INQ;
    const int t0 = qt * (SEGS * SLEN) + seg * SLEN;  // may exceed 2046: clamp below

    // Pipelined x: cur = x[min(t0,2047)], nxt = x[min(t0+1,2047)]
    float4 cur0, cur1, nxt0, nxt1;
    {
        int ta = t0;     if (ta > TT - 1) ta = TT - 1;
        int t1 = t0 + 1; if (t1 > TT - 1) t1 = TT - 1;
        const float4* p  = reinterpret_cast<const float4*>(xb + (size_t)ta * INQ);
        const float4* pn = reinterpret_cast<const float4*>(xb + (size_t)t1 * INQ);
        cur0 = p[0]; cur1 = p[1];
        nxt0 = pn[0]; nxt1 = pn[1];
    }

    #pragma unroll 1
    for (int s = 0; s < SLEN; ++s) {
        float dx[INQ];
        dx[0] = nxt0.x - cur0.x; dx[1] = nxt0.y - cur0.y;
        dx[2] = nxt0.z - cur0.z; dx[3] = nxt0.w - cur0.w;
        dx[4] = nxt1.x - cur1.x; dx[5] = nxt1.y - cur1.y;
        dx[6] = nxt1.z - cur1.z; dx[7] = nxt1.w - cur1.w;
        cur0 = nxt0; cur1 = nxt1;
        // prefetch step s+1's x; consumed next iteration (hides L2 latency
        // under this step's ~3.5k-cycle Taylor block)
        {
            int t2 = t0 + s + 2; if (t2 > TT - 1) t2 = TT - 1;
            const float4* pn = reinterpret_cast<const float4*>(xb + (size_t)t2 * INQ);
            nxt0 = pn[0]; nxt1 = pn[1];
        }

        // My 12 tri values: tv[u] = sum_ip dx[ip] * sktri[q*12+u][ip]
        float tv[12];
        #pragma unroll
        for (int u = 0; u < 12; ++u) {
            const float4* sp = reinterpret_cast<const float4*>(&sk_s[(q * 12 + u) * SKSTR]);
            const float4 s0 = sp[0], s1 = sp[1];
            tv[u] = dx[0] * s0.x + dx[1] * s0.y + dx[2] * s0.z + dx[3] * s0.w
                  + dx[4] * s1.x + dx[5] * s1.y + dx[6] * s1.z + dx[7] * s1.w;
        }

        // Assemble full Tri[45] per-lane via DPP quad broadcast:
        // global tri index U was computed by quad-lane U/12 at tv[U%12].
        float Tri[45];
        #define TRIFILL(U) Tri[U] = dpp_qbcast<(U) / 12>(tv[(U) % 12]);
        TRIFILL(0)  TRIFILL(1)  TRIFILL(2)  TRIFILL(3)  TRIFILL(4)
        TRIFILL(5)  TRIFILL(6)  TRIFILL(7)  TRIFILL(8)  TRIFILL(9)
        TRIFILL(10) TRIFILL(11) TRIFILL(12) TRIFILL(13) TRIFILL(14)
        TRIFILL(15) TRIFILL(16) TRIFILL(17) TRIFILL(18) TRIFILL(19)
        TRIFILL(20) TRIFILL(21) TRIFILL(22) TRIFILL(23) TRIFILL(24)
        TRIFILL(25) TRIFILL(26) TRIFILL(27) TRIFILL(28) TRIFILL(29)
        TRIFILL(30) TRIFILL(31) TRIFILL(32) TRIFILL(33) TRIFILL(34)
        TRIFILL(35) TRIFILL(36) TRIFILL(37) TRIFILL(38) TRIFILL(39)
        TRIFILL(40) TRIFILL(41) TRIFILL(42) TRIFILL(43) TRIFILL(44)
        #undef TRIFILL

        // G[k][j] = +Tri[triIdx(k,j)] (k<j), -Tri[triIdx(j,k)] (k>j), 0 diag.
        // Unnormalized Horner: Acc_j = Src*G; R += (1/j!)*Acc_j (ascending).
        float Acc[3][MM];

        #define TAYLOR_TERM(SRC, CJ)                                          \
        {                                                                     \
            _Pragma("unroll")                                                 \
            for (int r = 0; r < 3; ++r) {                                     \
                float tr[MM];                                                 \
                tr[0] = -SRC[r][1] * Tri[triIdx(0, 1)];                       \
                _Pragma("unroll")                                             \
                for (int j = 1; j < MM; ++j)                                  \
                    tr[j] = SRC[r][0] * Tri[triIdx(0, j)];                    \
                _Pragma("unroll")                                             \
                for (int k = 1; k < MM; ++k) {                                \
                    const float av = SRC[r][k];                               \
                    _Pragma("unroll")                                         \
                    for (int j = 0; j < MM; ++j) {                            \
                        if (k == j) continue;                                 \
                        if (j == 0 && k == 1) continue;                       \
                        if (j > k)      tr[j] += av * Tri[triIdx(k, j)];      \
                        else            tr[j] -= av * Tri[triIdx(j, k)];      \
                    }                                                         \
                }                                                             \
                _Pragma("unroll")                                             \
                for (int j = 0; j < MM; ++j) {                                \
                    Acc[r][j] = tr[j];                                        \
                    R[r][j]   = fmaf(CJ, tr[j], R[r][j]);                     \
                }                                                             \
            }                                                                 \
        }

        TAYLOR_TERM(R,   1.0f)                 // j=1
        TAYLOR_TERM(Acc, 0.5f)                 // j=2
        TAYLOR_TERM(Acc, 0.16666667f)          // j=3
        TAYLOR_TERM(Acc, 0.041666668f)         // j=4
        TAYLOR_TERM(Acc, 0.0083333338f)        // j=5
        TAYLOR_TERM(Acc, 0.0013888889f)        // j=6
        #undef TAYLOR_TERM
    }

    // Store segment product (real rows only) into tree region
    {
        float* dst = &buf_s[seg * MATS];
        #pragma unroll
        for (int r = 0; r < 3; ++r) {
            if (r < rc) {
                float4* drow = reinterpret_cast<float4*>(dst + (r0 + r) * ROWP);
                drow[0] = make_float4(R[r][0], R[r][1], R[r][2], R[r][3]);
                drow[1] = make_float4(R[r][4], R[r][5], R[r][6], R[r][7]);
                drow[2] = make_float4(R[r][8], R[r][9], 0.0f, 0.0f);
            }
        }
    }
    __syncthreads();

    // Pair-style dyadic tree, full 6 levels (64 -> 1 product at slot 0)
    #pragma unroll 1
    for (int span = 2; span <= SEGS; span <<= 1) {
        const int np = SEGS / span;
        if (tid < 2 * np) {
            const int pr = tid >> 1;
            const int pq = tid & 1;
            const int ls = pr * span;
            const int rs = ls + (span >> 1);

            float lrow[5][MM];
            #pragma unroll
            for (int r = 0; r < 5; ++r) {
                const float4* lr = reinterpret_cast<const float4*>(
                    &buf_s[ls * MATS + (pq * 5 + r) * ROWP]);
                const float4 a = lr[0], b = lr[1], c4 = lr[2];
                lrow[r][0] = a.x;  lrow[r][1] = a.y;  lrow[r][2] = a.z;  lrow[r][3] = a.w;
                lrow[r][4] = b.x;  lrow[r][5] = b.y;  lrow[r][6] = b.z;  lrow[r][7] = b.w;
                lrow[r][8] = c4.x; lrow[r][9] = c4.y;
            }

            float d[5][MM];
            #pragma unroll
            for (int r = 0; r < 5; ++r)
                #pragma unroll
                for (int j = 0; j < MM; ++j)
                    d[r][j] = 0.0f;

            #pragma unroll
            for (int k = 0; k < MM; ++k) {
                const float4* rr = reinterpret_cast<const float4*>(
                    &buf_s[rs * MATS + k * ROWP]);
                const float4 a = rr[0], b = rr[1], c4 = rr[2];
                float rrow[MM];
                rrow[0] = a.x;  rrow[1] = a.y;  rrow[2] = a.z;  rrow[3] = a.w;
                rrow[4] = b.x;  rrow[5] = b.y;  rrow[6] = b.z;  rrow[7] = b.w;
                rrow[8] = c4.x; rrow[9] = c4.y;
                #pragma unroll
                for (int r = 0; r < 5; ++r) {
                    const float lv = lrow[r][k];
                    #pragma unroll
                    for (int j = 0; j < MM; ++j)
                        d[r][j] += lv * rrow[j];
                }
            }

            float* dst = &buf_s[ls * MATS + pq * 5 * ROWP];
            #pragma unroll
            for (int r = 0; r < 5; ++r) {
                float4* drow = reinterpret_cast<float4*>(dst + r * ROWP);
                drow[0] = make_float4(d[r][0], d[r][1], d[r][2], d[r][3]);
                drow[1] = make_float4(d[r][4], d[r][5], d[r][6], d[r][7]);
                drow[2] = make_float4(d[r][8], d[r][9], 0.0f, 0.0f);
            }
        }
        __syncthreads();
    }

    // Chunk product -> ws, padded 120 floats at (chain*NCHUNK + qt)
    if (tid < 30) {
        const float4 v = reinterpret_cast<const float4*>(buf_s)[tid];
        reinterpret_cast<float4*>(ws)[((size_t)chain * NCHUNK + qt) * 30 + tid] = v;
    }
    __syncthreads();

    // Last-block combine (device-scope release/acquire via counter in ws).
    unsigned int* ctr = reinterpret_cast<unsigned int*>(ws + CTRO);
    if (tid == 0) {
        __threadfence();                       // release: ws product visible
        const unsigned int old = atomicAdd(ctr, 1u);
        last_s = (old == NBLK - 1) ? 1 : 0;
    }
    __syncthreads();
    if (last_s) {
        __threadfence();                       // acquire: see all blocks' ws
        // 2 lanes per chain: lane pq owns rows pq*5..pq*5+4
        const int ch = tid >> 1;
        const int pq = tid & 1;
        const float* base = ws + (size_t)ch * NCHUNK * WSMAT;

        float Rr[5][MM];
        #pragma unroll
        for (int r = 0; r < 5; ++r) {
            const float4* lr = reinterpret_cast<const float4*>(
                base + (pq * 5 + r) * ROWP);
            const float4 a = lr[0], b = lr[1], c4 = lr[2];
            Rr[r][0] = a.x;  Rr[r][1] = a.y;  Rr[r][2] = a.z;  Rr[r][3] = a.w;
            Rr[r][4] = b.x;  Rr[r][5] = b.y;  Rr[r][6] = b.z;  Rr[r][7] = b.w;
            Rr[r][8] = c4.x; Rr[r][9] = c4.y;
        }

        #pragma unroll 1
        for (int ck = 1; ck < NCHUNK; ++ck) {
            const float* B = base + ck * WSMAT;
            float d[5][MM];
            #pragma unroll
            for (int r = 0; r < 5; ++r)
                #pragma unroll
                for (int j = 0; j < MM; ++j)
                    d[r][j] = 0.0f;
            #pragma unroll
            for (int k = 0; k < MM; ++k) {
                const float4* br = reinterpret_cast<const float4*>(B + k * ROWP);
                const float4 a = br[0], b = br[1], c4 = br[2];
                float brow[MM];
                brow[0] = a.x;  brow[1] = a.y;  brow[2] = a.z;  brow[3] = a.w;
                brow[4] = b.x;  brow[5] = b.y;  brow[6] = b.z;  brow[7] = b.w;
                brow[8] = c4.x; brow[9] = c4.y;
                #pragma unroll
                for (int r = 0; r < 5; ++r) {
                    const float rv = Rr[r][k];
                    #pragma unroll
                    for (int j = 0; j < MM; ++j)
                        d[r][j] += rv * brow[j];
                }
            }
            #pragma unroll
            for (int r = 0; r < 5; ++r)
                #pragma unroll
                for (int j = 0; j < MM; ++j)
                    Rr[r][j] = d[r][j];
        }

        #pragma unroll
        for (int r = 0; r < 5; ++r)
            #pragma unroll
            for (int j = 0; j < MM; ++j)
                out[(size_t)ch * 100 + (pq * 5 + r) * 10 + j] = Rr[r][j];
    }
}

extern "C" void kernel_launch(void* const* d_in, const int* in_sizes, int n_in,
                              void* d_out, int out_size, void* d_ws, size_t ws_size,
                              hipStream_t stream) {
    (void)in_sizes; (void)n_in; (void)out_size; (void)ws_size;
    const float* x = (const float*)d_in[0];  // (64, 2048, 8)
    const float* A = (const float*)d_in[1];  // (2, 8, 10, 10)
    float* out = (float*)d_out;              // (64, 2, 10, 10)
    float* ws  = (float*)d_ws;               // 768 mats * 480 B + 4 B counter

    // zero the completion counter (ws is re-poisoned 0xAA before every call)
    hipMemsetAsync((char*)d_ws + CTRO * sizeof(float), 0, sizeof(unsigned int), stream);
    dev_serial<<<dim3(NBLK), dim3(256), 0, stream>>>(x, A, ws, out);
}

// Round 11
// 144.360 us; speedup vs baseline: 1.0485x; 1.0485x over previous
//
#include <hip/hip_runtime.h>

// Problem constants
#define NB     64      // batch
#define TT     2048    // time
#define INQ    8       // input size
#define CC     2       // channels
#define MM     10      // hidden m
#define ROWP   12      // padded row floats (48 B)
#define MATS   124     // matrix stride in LDS tree (124%32=28)
#define SKSTR  12      // sktri row stride floats
#define SLEN   6       // sequential steps per segment
#define SEGS   48      // segments per block (4 waves x 12 five-lane groups)
#define NCHUNK 8       // chunks per chain -> grid 1024 = 4 blocks/CU at <=128 VGPR
#define NCHAIN (NB*CC)
#define NBLK   (NCHAIN*NCHUNK)   // 1024

// Upper-triangle index for (k,j), k<j, into 45-element array
__device__ __forceinline__ constexpr int triIdx(int k, int j) {
    return k * 10 + j - ((k + 1) * (k + 2)) / 2;
}

// 2-lane pair combine: buf[ls] <- buf[ls] * buf[rs] (pq = which 5-row half)
__device__ __forceinline__ void pair_combine(float* buf_s, int ls, int rs, int pq) {
    float lrow[5][MM];
    #pragma unroll
    for (int r = 0; r < 5; ++r) {
        const float4* lr = reinterpret_cast<const float4*>(
            &buf_s[ls * MATS + (pq * 5 + r) * ROWP]);
        const float4 a = lr[0], b = lr[1], c4 = lr[2];
        lrow[r][0] = a.x;  lrow[r][1] = a.y;  lrow[r][2] = a.z;  lrow[r][3] = a.w;
        lrow[r][4] = b.x;  lrow[r][5] = b.y;  lrow[r][6] = b.z;  lrow[r][7] = b.w;
        lrow[r][8] = c4.x; lrow[r][9] = c4.y;
    }
    float d[5][MM];
    #pragma unroll
    for (int r = 0; r < 5; ++r)
        #pragma unroll
        for (int j = 0; j < MM; ++j)
            d[r][j] = 0.0f;
    #pragma unroll
    for (int k = 0; k < MM; ++k) {
        const float4* rr = reinterpret_cast<const float4*>(&buf_s[rs * MATS + k * ROWP]);
        const float4 a = rr[0], b = rr[1], c4 = rr[2];
        float rrow[MM];
        rrow[0] = a.x;  rrow[1] = a.y;  rrow[2] = a.z;  rrow[3] = a.w;
        rrow[4] = b.x;  rrow[5] = b.y;  rrow[6] = b.z;  rrow[7] = b.w;
        rrow[8] = c4.x; rrow[9] = c4.y;
        #pragma unroll
        for (int r = 0; r < 5; ++r) {
            const float lv = lrow[r][k];
            #pragma unroll
            for (int j = 0; j < MM; ++j)
                d[r][j] += lv * rrow[j];
        }
    }
    float* dst = &buf_s[ls * MATS + pq * 5 * ROWP];
    #pragma unroll
    for (int r = 0; r < 5; ++r) {
        float4* drow = reinterpret_cast<float4*>(dst + r * ROWP);
        drow[0] = make_float4(d[r][0], d[r][1], d[r][2], d[r][3]);
        drow[1] = make_float4(d[r][4], d[r][5], d[r][6], d[r][7]);
        drow[2] = make_float4(d[r][8], d[r][9], 0.0f, 0.0f);
    }
}

// One block per (chain, chunk). FIVE-lane groups own a segment each, 2 rows
// per lane (10 exact — kills the quad layout's 20% dummy-row waste) so the
// Taylor live set (R20+Acc20+Tri45+tr10+pipeline) fits <=128 VGPR -> the
// 4-waves/SIMD occupancy level. (Occupancy quantizes at VGPR {64,128,256}:
// r9 @160 VGPR ran 2 waves/SIMD; grids 768 were 1.5 ragged rounds at 2/CU —
// r7/r10 explained.) Tri exchange via ds_bpermute (5-lane groups aren't
// DPP-addressable). Lanes 60-63 of each wave idle (6%). Grid 1024 = 4/CU.
__global__ __launch_bounds__(256)
void dev_serial(const float* __restrict__ x,
                const float* __restrict__ A,
                float* __restrict__ ws)
{
    __shared__ __align__(16) float sk_s[48 * SKSTR];    // 2304 B (rows >=45 zero)
    __shared__ __align__(16) float buf_s[SEGS * MATS];  // 23808 B tree buffer

    const int tid   = threadIdx.x;
    const int chain = blockIdx.x >> 3;   // / NCHUNK
    const int qt    = blockIdx.x & 7;
    const int n     = chain >> 1;        // / CC
    const int c     = chain & 1;

    // Precompute sktri[t][ip] = A[c][ip][k][j] - A[c][ip][j][k], t <-> (k<j)
    for (int e = tid; e < 48 * INQ; e += 256) {
        const int t  = e >> 3;
        const int ip = e & 7;
        float v = 0.0f;
        if (t < 45) {
            int k = 0, rem = t;
            while (rem >= 9 - k) { rem -= (9 - k); ++k; }
            const int j = k + 1 + rem;
            const float* Ab = A + (size_t)(c * INQ + ip) * (MM * MM);
            v = Ab[k * MM + j] - Ab[j * MM + k];
        }
        sk_s[t * SKSTR + ip] = v;
    }
    for (int t = tid; t < 48; t += 256) {
        sk_s[t * SKSTR + 8]  = 0.0f; sk_s[t * SKSTR + 9]  = 0.0f;
        sk_s[t * SKSTR + 10] = 0.0f; sk_s[t * SKSTR + 11] = 0.0f;
    }
    __syncthreads();

    const int w    = tid >> 6;           // wave 0..3
    const int l    = tid & 63;           // lane in wave
    const int g    = l / 5;              // group 0..11 valid; 12 = idle lanes
    const int p5   = l - 5 * g;          // lane within group
    const bool act = (g < 12);
    const int seg  = w * 12 + (act ? g : 0);   // 0..47 (idle aliases seg of g0)
    const int r0   = 2 * p5;             // rows r0, r0+1
    const int base = l - p5;             // group base lane (wave-local)

    // Running product rows (identity)
    float R[2][MM];
    #pragma unroll
    for (int r = 0; r < 2; ++r)
        #pragma unroll
        for (int j = 0; j < MM; ++j)
            R[r][j] = (j == r0 + r) ? 1.0f : 0.0f;

    const float* xb = x + (size_t)n * TT * INQ;
    const int t0 = qt * (SEGS * SLEN) + (w * 12 + g) * SLEN;  // may exceed 2047

    // Pipelined x: cur = x[min(t0,2047)], nxt = x[min(t0+1,2047)]
    float4 cur0, cur1, nxt0, nxt1;
    {
        int ta = t0;     if (ta > TT - 1) ta = TT - 1; if (ta < 0) ta = 0;
        int t1 = t0 + 1; if (t1 > TT - 1) t1 = TT - 1; if (t1 < 0) t1 = 0;
        const float4* p  = reinterpret_cast<const float4*>(xb + (size_t)ta * INQ);
        const float4* pn = reinterpret_cast<const float4*>(xb + (size_t)t1 * INQ);
        cur0 = p[0]; cur1 = p[1];
        nxt0 = pn[0]; nxt1 = pn[1];
    }

    #pragma unroll 1
    for (int s = 0; s < SLEN; ++s) {
        float dx[INQ];
        dx[0] = nxt0.x - cur0.x; dx[1] = nxt0.y - cur0.y;
        dx[2] = nxt0.z - cur0.z; dx[3] = nxt0.w - cur0.w;
        dx[4] = nxt1.x - cur1.x; dx[5] = nxt1.y - cur1.y;
        dx[6] = nxt1.z - cur1.z; dx[7] = nxt1.w - cur1.w;
        cur0 = nxt0; cur1 = nxt1;
        // prefetch step s+1's x; consumed next iteration
        {
            int t2 = t0 + s + 2;
            if (t2 > TT - 1) t2 = TT - 1; if (t2 < 0) t2 = 0;
            const float4* pn = reinterpret_cast<const float4*>(xb + (size_t)t2 * INQ);
            nxt0 = pn[0]; nxt1 = pn[1];
        }

        // My 9 tri values: tv[u] = sum_ip dx[ip] * sktri[p5*9+u][ip]
        // (12 groups read identical rows -> LDS broadcast, conflict-free)
        float tv[9];
        #pragma unroll
        for (int u = 0; u < 9; ++u) {
            const float4* sp = reinterpret_cast<const float4*>(&sk_s[(p5 * 9 + u) * SKSTR]);
            const float4 s0 = sp[0], s1 = sp[1];
            tv[u] = dx[0] * s0.x + dx[1] * s0.y + dx[2] * s0.z + dx[3] * s0.w
                  + dx[4] * s1.x + dx[5] * s1.y + dx[6] * s1.z + dx[7] * s1.w;
        }

        // Assemble Tri[45] per-lane via ds_bpermute within the 5-lane group:
        // tri U lives on group-lane U/9, register tv[U%9].
        float Tri[45];
        #define TRIFILL(U) Tri[U] = __int_as_float(__builtin_amdgcn_ds_bpermute( \
            4 * (base + (U) / 9), __float_as_int(tv[(U) % 9])));
        TRIFILL(0)  TRIFILL(1)  TRIFILL(2)  TRIFILL(3)  TRIFILL(4)
        TRIFILL(5)  TRIFILL(6)  TRIFILL(7)  TRIFILL(8)  TRIFILL(9)
        TRIFILL(10) TRIFILL(11) TRIFILL(12) TRIFILL(13) TRIFILL(14)
        TRIFILL(15) TRIFILL(16) TRIFILL(17) TRIFILL(18) TRIFILL(19)
        TRIFILL(20) TRIFILL(21) TRIFILL(22) TRIFILL(23) TRIFILL(24)
        TRIFILL(25) TRIFILL(26) TRIFILL(27) TRIFILL(28) TRIFILL(29)
        TRIFILL(30) TRIFILL(31) TRIFILL(32) TRIFILL(33) TRIFILL(34)
        TRIFILL(35) TRIFILL(36) TRIFILL(37) TRIFILL(38) TRIFILL(39)
        TRIFILL(40) TRIFILL(41) TRIFILL(42) TRIFILL(43) TRIFILL(44)
        #undef TRIFILL

        // G[k][j] = +Tri[triIdx(k,j)] (k<j), -Tri[triIdx(j,k)] (k>j), 0 diag.
        // Unnormalized Horner: Acc_j = Src*G; R += (1/j!)*Acc_j (ascending).
        float Acc[2][MM];

        #define TAYLOR_TERM(SRC, CJ)                                          \
        {                                                                     \
            _Pragma("unroll")                                                 \
            for (int r = 0; r < 2; ++r) {                                     \
                float tr[MM];                                                 \
                tr[0] = -SRC[r][1] * Tri[triIdx(0, 1)];                       \
                _Pragma("unroll")                                             \
                for (int j = 1; j < MM; ++j)                                  \
                    tr[j] = SRC[r][0] * Tri[triIdx(0, j)];                    \
                _Pragma("unroll")                                             \
                for (int k = 1; k < MM; ++k) {                                \
                    const float av = SRC[r][k];                               \
                    _Pragma("unroll")                                         \
                    for (int j = 0; j < MM; ++j) {                            \
                        if (k == j) continue;                                 \
                        if (j == 0 && k == 1) continue;                       \
                        if (j > k)      tr[j] += av * Tri[triIdx(k, j)];      \
                        else            tr[j] -= av * Tri[triIdx(j, k)];      \
                    }                                                         \
                }                                                             \
                _Pragma("unroll")                                             \
                for (int j = 0; j < MM; ++j) {                                \
                    Acc[r][j] = tr[j];                                        \
                    R[r][j]   = fmaf(CJ, tr[j], R[r][j]);                     \
                }                                                             \
            }                                                                 \
        }

        TAYLOR_TERM(R,   1.0f)                 // j=1
        TAYLOR_TERM(Acc, 0.5f)                 // j=2
        TAYLOR_TERM(Acc, 0.16666667f)          // j=3
        TAYLOR_TERM(Acc, 0.041666668f)         // j=4
        TAYLOR_TERM(Acc, 0.0083333338f)        // j=5
        TAYLOR_TERM(Acc, 0.0013888889f)        // j=6
        #undef TAYLOR_TERM
    }

    // Store segment product rows (active lanes only)
    if (act) {
        float* dst = &buf_s[seg * MATS];
        #pragma unroll
        for (int r = 0; r < 2; ++r) {
            float4* drow = reinterpret_cast<float4*>(dst + (r0 + r) * ROWP);
            drow[0] = make_float4(R[r][0], R[r][1], R[r][2], R[r][3]);
            drow[1] = make_float4(R[r][4], R[r][5], R[r][6], R[r][7]);
            drow[2] = make_float4(R[r][8], R[r][9], 0.0f, 0.0f);
        }
    }
    __syncthreads();

    // Dyadic pair tree over 48 slots: spans 2,4,8,16 -> survivors 0,16,32
    #pragma unroll 1
    for (int span = 2; span <= 16; span <<= 1) {
        const int np = SEGS / span;
        if (tid < 2 * np) {
            const int pr = tid >> 1;
            const int pq = tid & 1;
            pair_combine(buf_s, pr * span, pr * span + (span >> 1), pq);
        }
        __syncthreads();
    }
    // Final: slot0 <- slot0*slot16, then slot0 <- slot0*slot32 (time order)
    #pragma unroll 1
    for (int fin = 0; fin < 2; ++fin) {
        if (tid < 2)
            pair_combine(buf_s, 0, 16 + 16 * fin, tid);
        __syncthreads();
    }

    // Chunk product -> ws, padded 120 floats at (chain*NCHUNK + qt)
    if (tid < 30) {
        const float4 v = reinterpret_cast<const float4*>(buf_s)[tid];
        reinterpret_cast<float4*>(ws)[((size_t)chain * NCHUNK + qt) * 30 + tid] = v;
    }
}

// K2: one block per chain; combine its 8 chunk products (time order)
// with a 3-level LDS tree, write the 10x10 result to out.
__global__ __launch_bounds__(256)
void dev_tree8(const float* __restrict__ ws, float* __restrict__ out)
{
    __shared__ __align__(16) float buf_s[8 * MATS];
    const int tid   = threadIdx.x;
    const int chain = blockIdx.x;

    if (tid < 240) {
        const int m  = tid / 30;
        const int o4 = tid - m * 30;
        const float4 v = reinterpret_cast<const float4*>(ws)[((size_t)chain * 8 + m) * 30 + o4];
        reinterpret_cast<float4*>(&buf_s[m * MATS])[o4] = v;
    }
    __syncthreads();

    #pragma unroll 1
    for (int span = 2; span <= 8; span <<= 1) {
        const int np = 8 / span;
        if (tid < 2 * np) {
            const int pr = tid >> 1;
            const int pq = tid & 1;
            pair_combine(buf_s, pr * span, pr * span + (span >> 1), pq);
        }
        __syncthreads();
    }

    if (tid < 100) {
        const int i = tid / 10;
        const int j = tid - i * 10;
        out[(size_t)chain * 100 + tid] = buf_s[i * ROWP + j];
    }
}

extern "C" void kernel_launch(void* const* d_in, const int* in_sizes, int n_in,
                              void* d_out, int out_size, void* d_ws, size_t ws_size,
                              hipStream_t stream) {
    (void)in_sizes; (void)n_in; (void)out_size; (void)ws_size;
    const float* x = (const float*)d_in[0];  // (64, 2048, 8)
    const float* A = (const float*)d_in[1];  // (2, 8, 10, 10)
    float* out = (float*)d_out;              // (64, 2, 10, 10)
    float* ws  = (float*)d_ws;               // 1024 mats * 480 B = 491,520 B

    dev_serial<<<dim3(NBLK), dim3(256), 0, stream>>>(x, A, ws);
    dev_tree8<<<dim3(NCHAIN), dim3(256), 0, stream>>>(ws, out);
}

// Round 12
// 114.986 us; speedup vs baseline: 1.3163x; 1.2555x over previous
//
#include <hip/hip_runtime.h>

// Problem constants
#define NB     64      // batch
#define TT     2048    // time
#define INQ    8       // input size
#define CC     2       // channels
#define MM     10      // hidden m
#define ROWP   12      // padded row floats (48 B)
#define MATS   124     // matrix stride in LDS tree (124%32=28)
#define PSTR   20      // sktri pair-row stride floats (q spacing 120%32=24, 16B-aligned)
#define SLEN   8       // sequential steps per quad segment
#define SEGS   64      // segments per block (256 thr / 4 lanes)
#define NCHUNK 4       // quarters per chain -> grid 512 = 1 clean round at 2 blocks/CU
#define NCHAIN (NB*CC)

typedef float v2f __attribute__((ext_vector_type(2)));

// Upper-triangle index for (k,j), k<j, into 45-element array
__device__ __forceinline__ constexpr int triIdx(int k, int j) {
    return k * 10 + j - ((k + 1) * (k + 2)) / 2;
}

// Broadcast lane (quad base + SRC)'s value to all 4 lanes of the quad.
template <int SRC>
__device__ __forceinline__ float dpp_qbcast(float v) {
    const int i = __float_as_int(v);
    const int r = __builtin_amdgcn_update_dpp(i, i, SRC * 0x55, 0xF, 0xF, true);
    return __int_as_float(r);
}

// 2-lane pair combine: buf[ls] <- buf[ls] * buf[rs] (pq = which 5-row half)
__device__ __forceinline__ void pair_combine(float* buf_s, int ls, int rs, int pq) {
    float lrow[5][MM];
    #pragma unroll
    for (int r = 0; r < 5; ++r) {
        const float4* lr = reinterpret_cast<const float4*>(
            &buf_s[ls * MATS + (pq * 5 + r) * ROWP]);
        const float4 a = lr[0], b = lr[1], c4 = lr[2];
        lrow[r][0] = a.x;  lrow[r][1] = a.y;  lrow[r][2] = a.z;  lrow[r][3] = a.w;
        lrow[r][4] = b.x;  lrow[r][5] = b.y;  lrow[r][6] = b.z;  lrow[r][7] = b.w;
        lrow[r][8] = c4.x; lrow[r][9] = c4.y;
    }
    float d[5][MM];
    #pragma unroll
    for (int r = 0; r < 5; ++r)
        #pragma unroll
        for (int j = 0; j < MM; ++j)
            d[r][j] = 0.0f;
    #pragma unroll
    for (int k = 0; k < MM; ++k) {
        const float4* rr = reinterpret_cast<const float4*>(&buf_s[rs * MATS + k * ROWP]);
        const float4 a = rr[0], b = rr[1], c4 = rr[2];
        float rrow[MM];
        rrow[0] = a.x;  rrow[1] = a.y;  rrow[2] = a.z;  rrow[3] = a.w;
        rrow[4] = b.x;  rrow[5] = b.y;  rrow[6] = b.z;  rrow[7] = b.w;
        rrow[8] = c4.x; rrow[9] = c4.y;
        #pragma unroll
        for (int r = 0; r < 5; ++r) {
            const float lv = lrow[r][k];
            #pragma unroll
            for (int j = 0; j < MM; ++j)
                d[r][j] += lv * rrow[j];
        }
    }
    float* dst = &buf_s[ls * MATS + pq * 5 * ROWP];
    #pragma unroll
    for (int r = 0; r < 5; ++r) {
        float4* drow = reinterpret_cast<float4*>(dst + r * ROWP);
        drow[0] = make_float4(d[r][0], d[r][1], d[r][2], d[r][3]);
        drow[1] = make_float4(d[r][4], d[r][5], d[r][6], d[r][7]);
        drow[2] = make_float4(d[r][8], d[r][9], 0.0f, 0.0f);
    }
}

// One block per (chain, quarter) — r9 structure (best: 73.8 µs serial,
// grid 512 = one clean round at the 2-waves/SIMD occupancy level; cliffs
// at VGPR {64,128,256} put all our 136-176 variants on 2 waves).
// NEW: Taylor core packed for v_pk_fma_f32 — each lane's first two rows as
// float2 ext-vectors (R01/Acc01), third row scalar. Quad rows: q0 {0,1}+2,
// q1 {3,4}+5, q2 {6,7}(+dummy), q3 {8,9}(+dummy). tv also packed via a
// pair-interleaved sktri layout. Expected ~30% fewer VALU issues per step.
__global__ __launch_bounds__(256)
void dev_serial(const float* __restrict__ x,
                const float* __restrict__ A,
                float* __restrict__ ws)
{
    __shared__ __align__(16) float skp_s[24 * PSTR];    // 1920 B pair-interleaved
    __shared__ __align__(16) float buf_s[SEGS * MATS];  // 31744 B tree buffer

    const int tid   = threadIdx.x;
    const int chain = blockIdx.x >> 2;   // / NCHUNK
    const int qt    = blockIdx.x & 3;
    const int n     = chain >> 1;        // / CC
    const int c     = chain & 1;

    // skp[p][ip] = v2f{ sktri[2p][ip], sktri[2p+1][ip] }, rows >=45 zero.
    // float layout: p*PSTR + 2*ip + h, pad floats 16..19 zero.
    for (int e = tid; e < 24 * 16; e += 256) {
        const int p   = e >> 4;
        const int rem = e & 15;
        const int ip  = rem >> 1;
        const int h   = rem & 1;
        const int t   = 2 * p + h;
        float v = 0.0f;
        if (t < 45) {
            int k = 0, r2 = t;
            while (r2 >= 9 - k) { r2 -= (9 - k); ++k; }
            const int j = k + 1 + r2;
            const float* Ab = A + (size_t)(c * INQ + ip) * (MM * MM);
            v = Ab[k * MM + j] - Ab[j * MM + k];
        }
        skp_s[p * PSTR + 2 * ip + h] = v;
    }
    for (int p = tid; p < 24; p += 256) {
        skp_s[p * PSTR + 16] = 0.0f; skp_s[p * PSTR + 17] = 0.0f;
        skp_s[p * PSTR + 18] = 0.0f; skp_s[p * PSTR + 19] = 0.0f;
    }
    __syncthreads();

    const int seg = tid >> 2;
    const int q   = tid & 3;                        // lane within quad
    const int p0  = (q < 2) ? 3 * q : (q == 2 ? 6 : 8);  // packed pair rows p0,p0+1
    const int sr  = (q < 2) ? (3 * q + 2) : 9;      // scalar row (dummy on q>=2)
    const bool hasS = (q < 2);

    // Running product: rows p0,p0+1 packed; row sr scalar.
    v2f   R01[MM];
    float R2[MM];
    #pragma unroll
    for (int j = 0; j < MM; ++j) {
        R01[j] = (v2f){ (j == p0) ? 1.0f : 0.0f, (j == p0 + 1) ? 1.0f : 0.0f };
        R2[j]  = (j == sr) ? 1.0f : 0.0f;
    }

    const float* xb = x + (size_t)n * TT * INQ;
    const int t0 = qt * (SEGS * SLEN) + seg * SLEN;   // max t0+7 = 2047

    // Pipelined x
    float4 cur0, cur1, nxt0, nxt1;
    {
        const float4* p = reinterpret_cast<const float4*>(xb + (size_t)t0 * INQ);
        cur0 = p[0]; cur1 = p[1];
        int t1 = t0 + 1; if (t1 > TT - 1) t1 = TT - 1;
        const float4* pn = reinterpret_cast<const float4*>(xb + (size_t)t1 * INQ);
        nxt0 = pn[0]; nxt1 = pn[1];
    }

    #pragma unroll 1
    for (int s = 0; s < SLEN; ++s) {
        float dx[INQ];
        dx[0] = nxt0.x - cur0.x; dx[1] = nxt0.y - cur0.y;
        dx[2] = nxt0.z - cur0.z; dx[3] = nxt0.w - cur0.w;
        dx[4] = nxt1.x - cur1.x; dx[5] = nxt1.y - cur1.y;
        dx[6] = nxt1.z - cur1.z; dx[7] = nxt1.w - cur1.w;
        cur0 = nxt0; cur1 = nxt1;
        {
            int t2 = t0 + s + 2; if (t2 > TT - 1) t2 = TT - 1;
            const float4* pn = reinterpret_cast<const float4*>(xb + (size_t)t2 * INQ);
            nxt0 = pn[0]; nxt1 = pn[1];
        }

        // Packed tv: tvp[pp] = (tri[12q+2pp], tri[12q+2pp+1]) = sum_ip dx[ip]*skp
        v2f tvp[6];
        #pragma unroll
        for (int pp = 0; pp < 6; ++pp) {
            const v2f* sp = reinterpret_cast<const v2f*>(&skp_s[(6 * q + pp) * PSTR]);
            v2f acc = dx[0] * sp[0];
            #pragma unroll
            for (int ip = 1; ip < INQ; ++ip)
                acc += dx[ip] * sp[ip];
            tvp[pp] = acc;
        }
        float tv[12];
        #pragma unroll
        for (int pp = 0; pp < 6; ++pp) { tv[2 * pp] = tvp[pp].x; tv[2 * pp + 1] = tvp[pp].y; }

        // Assemble Tri[45] per-lane via DPP quad broadcast (tri U from lane U/12)
        float Tri[45];
        #define TRIFILL(U) Tri[U] = dpp_qbcast<(U) / 12>(tv[(U) % 12]);
        TRIFILL(0)  TRIFILL(1)  TRIFILL(2)  TRIFILL(3)  TRIFILL(4)
        TRIFILL(5)  TRIFILL(6)  TRIFILL(7)  TRIFILL(8)  TRIFILL(9)
        TRIFILL(10) TRIFILL(11) TRIFILL(12) TRIFILL(13) TRIFILL(14)
        TRIFILL(15) TRIFILL(16) TRIFILL(17) TRIFILL(18) TRIFILL(19)
        TRIFILL(20) TRIFILL(21) TRIFILL(22) TRIFILL(23) TRIFILL(24)
        TRIFILL(25) TRIFILL(26) TRIFILL(27) TRIFILL(28) TRIFILL(29)
        TRIFILL(30) TRIFILL(31) TRIFILL(32) TRIFILL(33) TRIFILL(34)
        TRIFILL(35) TRIFILL(36) TRIFILL(37) TRIFILL(38) TRIFILL(39)
        TRIFILL(40) TRIFILL(41) TRIFILL(42) TRIFILL(43) TRIFILL(44)
        #undef TRIFILL

        // G[k][j] = +Tri[triIdx(k,j)] (k<j), -Tri[triIdx(j,k)] (k>j), 0 diag.
        // Unnormalized Horner, packed: rows (p0,p0+1) as v2f, row sr scalar.
        v2f   Acc01[MM];
        float Acc2[MM];

        #define TAYLOR_TERM(S01, S2, CJ)                                      \
        {                                                                     \
            v2f   t01[MM];                                                    \
            float t2[MM];                                                     \
            t01[0] = -S01[1] * Tri[triIdx(0, 1)];                             \
            t2[0]  = -S2[1]  * Tri[triIdx(0, 1)];                             \
            _Pragma("unroll")                                                 \
            for (int j = 1; j < MM; ++j) {                                    \
                t01[j] = S01[0] * Tri[triIdx(0, j)];                          \
                t2[j]  = S2[0]  * Tri[triIdx(0, j)];                          \
            }                                                                 \
            _Pragma("unroll")                                                 \
            for (int k = 1; k < MM; ++k) {                                    \
                const v2f   a01 = S01[k];                                     \
                const float a2  = S2[k];                                      \
                _Pragma("unroll")                                             \
                for (int j = 0; j < MM; ++j) {                                \
                    if (k == j) continue;                                     \
                    if (j == 0 && k == 1) continue;                           \
                    if (j > k) {                                              \
                        const float t = Tri[triIdx(k, j)];                    \
                        t01[j] += a01 * t;                                    \
                        t2[j]  += a2 * t;                                     \
                    } else {                                                  \
                        const float t = Tri[triIdx(j, k)];                    \
                        t01[j] -= a01 * t;                                    \
                        t2[j]  -= a2 * t;                                     \
                    }                                                         \
                }                                                             \
            }                                                                 \
            _Pragma("unroll")                                                 \
            for (int j = 0; j < MM; ++j) {                                    \
                Acc01[j] = t01[j];                                            \
                Acc2[j]  = t2[j];                                             \
                R01[j]  += CJ * t01[j];                                       \
                R2[j]   += CJ * t2[j];                                        \
            }                                                                 \
        }

        TAYLOR_TERM(R01,   R2,   1.0f)            // j=1
        TAYLOR_TERM(Acc01, Acc2, 0.5f)            // j=2
        TAYLOR_TERM(Acc01, Acc2, 0.16666667f)     // j=3
        TAYLOR_TERM(Acc01, Acc2, 0.041666668f)    // j=4
        TAYLOR_TERM(Acc01, Acc2, 0.0083333338f)   // j=5
        TAYLOR_TERM(Acc01, Acc2, 0.0013888889f)   // j=6
        #undef TAYLOR_TERM
    }

    // Store segment product: packed pair rows from all lanes, scalar row from q<2
    {
        float* dst = &buf_s[seg * MATS];
        float4* d0 = reinterpret_cast<float4*>(dst + p0 * ROWP);
        d0[0] = make_float4(R01[0].x, R01[1].x, R01[2].x, R01[3].x);
        d0[1] = make_float4(R01[4].x, R01[5].x, R01[6].x, R01[7].x);
        d0[2] = make_float4(R01[8].x, R01[9].x, 0.0f, 0.0f);
        float4* d1 = reinterpret_cast<float4*>(dst + (p0 + 1) * ROWP);
        d1[0] = make_float4(R01[0].y, R01[1].y, R01[2].y, R01[3].y);
        d1[1] = make_float4(R01[4].y, R01[5].y, R01[6].y, R01[7].y);
        d1[2] = make_float4(R01[8].y, R01[9].y, 0.0f, 0.0f);
        if (hasS) {
            float4* d2 = reinterpret_cast<float4*>(dst + sr * ROWP);
            d2[0] = make_float4(R2[0], R2[1], R2[2], R2[3]);
            d2[1] = make_float4(R2[4], R2[5], R2[6], R2[7]);
            d2[2] = make_float4(R2[8], R2[9], 0.0f, 0.0f);
        }
    }
    __syncthreads();

    // Pair-style dyadic tree, full 6 levels (64 -> 1 product at slot 0)
    #pragma unroll 1
    for (int span = 2; span <= SEGS; span <<= 1) {
        const int np = SEGS / span;
        if (tid < 2 * np) {
            const int pr = tid >> 1;
            const int pq = tid & 1;
            pair_combine(buf_s, pr * span, pr * span + (span >> 1), pq);
        }
        __syncthreads();
    }

    // Chunk product -> ws, padded 120 floats at (chain*NCHUNK + qt)
    if (tid < 30) {
        const float4 v = reinterpret_cast<const float4*>(buf_s)[tid];
        reinterpret_cast<float4*>(ws)[((size_t)chain * NCHUNK + qt) * 30 + tid] = v;
    }
}

// K2: one block per chain; combine its 4 chunk products (time order)
__global__ __launch_bounds__(256)
void dev_tree4(const float* __restrict__ ws, float* __restrict__ out)
{
    __shared__ __align__(16) float buf_s[4 * MATS];
    const int tid   = threadIdx.x;
    const int chain = blockIdx.x;

    if (tid < 120) {
        const int m  = tid / 30;
        const int o4 = tid - m * 30;
        const float4 v = reinterpret_cast<const float4*>(ws)[((size_t)chain * 4 + m) * 30 + o4];
        reinterpret_cast<float4*>(&buf_s[m * MATS])[o4] = v;
    }
    __syncthreads();

    if (tid < 4)
        pair_combine(buf_s, (tid >> 1) * 2, (tid >> 1) * 2 + 1, tid & 1);
    __syncthreads();
    if (tid < 2)
        pair_combine(buf_s, 0, 2, tid);
    __syncthreads();

    if (tid < 100) {
        const int i = tid / 10;
        const int j = tid - i * 10;
        out[(size_t)chain * 100 + tid] = buf_s[i * ROWP + j];
    }
}

extern "C" void kernel_launch(void* const* d_in, const int* in_sizes, int n_in,
                              void* d_out, int out_size, void* d_ws, size_t ws_size,
                              hipStream_t stream) {
    (void)in_sizes; (void)n_in; (void)out_size; (void)ws_size;
    const float* x = (const float*)d_in[0];  // (64, 2048, 8)
    const float* A = (const float*)d_in[1];  // (2, 8, 10, 10)
    float* out = (float*)d_out;              // (64, 2, 10, 10)
    float* ws  = (float*)d_ws;               // 512 mats * 480 B = 245,760 B

    dev_serial<<<dim3(NCHAIN * NCHUNK), dim3(256), 0, stream>>>(x, A, ws);
    dev_tree4<<<dim3(NCHAIN), dim3(256), 0, stream>>>(ws, out);
}